// Round 6
// baseline (504.710 us; speedup 1.0000x reference)
//
#include <hip/hip_runtime.h>

// GCN block: delta = segment_sum( (x @ W^T)[source] * ew, target )
//          = segment_sum( x[source] * ew, target ) @ W^T   (linearity)
//
// R6: bucket-granular counting sort (BKT=128 nodes/bucket) + LDS-accumulated
// bucket reduce. Kills R5's two costs:
//  - 1M random global atomics (hist + cursor)  -> LDS-binned hists, ~200K
//    line-clustered reserve atomics
//  - 8x write-amplified pair scatter (65 MB)   -> per-(block,bucket)
//    contiguous runs (~20 MB)
// Reduce kernel: per-bucket 128x64 f32 LDS accumulator + ds f32 atomics
// (no per-node ordering needed), fused 64x64 GEMM epilogue.

#define D    64     // D_IN == D_OUT == 64
#define BKT  128    // nodes per bucket (t >> 7)
#define NBMAX 1024  // max buckets supported by scan kernel

// ---------------- fallback: atomic edge scatter (R1) ----------------
__global__ __launch_bounds__(256) void gcn_scatter_kernel(
    const float* __restrict__ x, const float* __restrict__ ew,
    const int* __restrict__ src, const int* __restrict__ tgt,
    float* __restrict__ s, int n_edges)
{
    int lane = threadIdx.x & 63;
    int e = blockIdx.x * 4 + (threadIdx.x >> 6);
    if (e >= n_edges) return;
    int sn = src[e];
    int tn = tgt[e];
    float w = ew[e];
    float v = x[(size_t)sn * D + lane] * w;
    atomicAdd(&s[(size_t)tn * D + lane], v);
}

// ---------------- fallback: out = s @ W^T (R1) ----------------
__global__ __launch_bounds__(256) void gcn_gemm_kernel(
    const float* __restrict__ s, const float* __restrict__ W,
    float* __restrict__ out, int n_nodes)
{
    __shared__ float4 xs[64 * 17];
    const int tid  = threadIdx.x;
    const int lane = tid & 63;
    const int wid  = __builtin_amdgcn_readfirstlane(tid >> 6);
    const int row0 = blockIdx.x * 64;

    const float4* s4 = reinterpret_cast<const float4*>(s);
#pragma unroll
    for (int k = 0; k < 4; ++k) {
        int f  = tid + k * 256;
        int r  = f >> 4;
        int c4 = f & 15;
        float4 v = make_float4(0.f, 0.f, 0.f, 0.f);
        if (row0 + r < n_nodes)
            v = s4[(size_t)(row0 + r) * 16 + c4];
        xs[r * 17 + c4] = v;
    }
    __syncthreads();

    float acc[16];
#pragma unroll
    for (int j = 0; j < 16; ++j) acc[j] = 0.f;

    const int o0 = wid * 16;
    const float4* W4 = reinterpret_cast<const float4*>(W);
#pragma unroll
    for (int d4 = 0; d4 < 16; ++d4) {
        float4 xv = xs[lane * 17 + d4];
#pragma unroll
        for (int j = 0; j < 16; ++j) {
            float4 wv = W4[(size_t)(o0 + j) * 16 + d4];
            acc[j] += xv.x * wv.x + xv.y * wv.y + xv.z * wv.z + xv.w * wv.w;
        }
    }

    const int row = row0 + lane;
    if (row < n_nodes) {
        float4* out4 = reinterpret_cast<float4*>(out);
#pragma unroll
        for (int j4 = 0; j4 < 4; ++j4) {
            float4 v = make_float4(acc[j4 * 4 + 0], acc[j4 * 4 + 1],
                                   acc[j4 * 4 + 2], acc[j4 * 4 + 3]);
            out4[(size_t)row * 16 + wid * 4 + j4] = v;
        }
    }
}

// ---------------- A: bucket histogram (LDS-binned) ----------------
__global__ __launch_bounds__(256) void bucket_hist_kernel(
    const int* __restrict__ tgt, int* __restrict__ bcnt,
    int n_edges, int nb, int epb)
{
    __shared__ int h[NBMAX];
    const int tid = threadIdx.x;
    for (int i = tid; i < nb; i += 256) h[i] = 0;
    __syncthreads();
    const int e0 = blockIdx.x * epb;
    const int e1 = min(e0 + epb, n_edges);
    for (int e = e0 + tid; e < e1; e += 256)
        atomicAdd(&h[tgt[e] >> 7], 1);
    __syncthreads();
    for (int b = tid; b < nb; b += 256) {
        int c = h[b];
        if (c) atomicAdd(&bcnt[b], c);
    }
}

// ---------------- B: exclusive scan of bucket counts (nb <= 1024) ----------
__global__ __launch_bounds__(1024) void bucket_scan_kernel(
    const int* __restrict__ bcnt, int* __restrict__ bstarts,
    int* __restrict__ bcur, int nb)
{
    __shared__ int lds[1024];
    const int tid = threadIdx.x;
    int v = (tid < nb) ? bcnt[tid] : 0;
    lds[tid] = v;
    __syncthreads();
    for (int off = 1; off < 1024; off <<= 1) {
        int a = (tid >= off) ? lds[tid - off] : 0;
        __syncthreads();
        lds[tid] += a;
        __syncthreads();
    }
    if (tid < nb) {
        int st = lds[tid] - v;       // exclusive
        bstarts[tid] = st;
        bcur[tid]    = st;
    }
}

// ---------------- C: scatter edges into bucket-contiguous runs ----------
// Two passes over a contiguous edge range: LDS hist -> reserve runs via one
// global atomic per (block,bucket) -> write packed (tloc<<24|src, ew).
__global__ __launch_bounds__(256) void bucket_scatter_kernel(
    const int* __restrict__ src, const int* __restrict__ tgt,
    const float* __restrict__ ew, int* __restrict__ bcur,
    int2* __restrict__ pairs, int n_edges, int nb, int epb)
{
    __shared__ int h[NBMAX];        // counts, then rank counters
    __shared__ int base[NBMAX];
    const int tid = threadIdx.x;
    for (int i = tid; i < nb; i += 256) h[i] = 0;
    __syncthreads();
    const int e0 = blockIdx.x * epb;
    const int e1 = min(e0 + epb, n_edges);

    for (int e = e0 + tid; e < e1; e += 256)
        atomicAdd(&h[tgt[e] >> 7], 1);
    __syncthreads();

    for (int b = tid; b < nb; b += 256) {
        int c = h[b];
        base[b] = c ? atomicAdd(&bcur[b], c) : 0;
        h[b] = 0;                   // reuse as rank counter
    }
    __syncthreads();

    for (int e = e0 + tid; e < e1; e += 256) {
        int t = tgt[e];
        int b = t >> 7;
        int r = atomicAdd(&h[b], 1);
        pairs[base[b] + r] =
            make_int2(((t & (BKT - 1)) << 24) | src[e], __float_as_int(ew[e]));
    }
}

// ---------------- D: per-bucket LDS reduce + fused GEMM epilogue ----------
// One block per bucket (128 nodes). 8 waves stream the bucket's edges:
// wave-uniform scalar pair loads, 8-deep independent x-row gathers,
// ds f32 atomic add into acc[tloc][lane] (64 consecutive floats: 2-way
// bank alias = free; cross-wave same-target collisions are safe via
// atomicity). Epilogue: out[t] = acc[t] @ W^T with W in LDS (pad 66).
__global__ __launch_bounds__(512) void bucket_reduce_gemm_kernel(
    const float* __restrict__ x, const float* __restrict__ W,
    const int* __restrict__ bstarts, const int2* __restrict__ pairs,
    float* __restrict__ out, int n_nodes, int n_edges, int nb)
{
    __shared__ __align__(16) float Wl[64 * 66];   // W[o][d] at Wl[o*66+d]
    __shared__ __align__(16) float acc[BKT * D];  // 32 KB

    const int tid  = threadIdx.x;
    const int lane = tid & 63;
    const int wv   = tid >> 6;                    // 0..7

    for (int i = tid; i < 64 * 64; i += 512)
        Wl[(i >> 6) * 66 + (i & 63)] = W[i];
    for (int i = tid; i < BKT * D; i += 512) acc[i] = 0.f;
    __syncthreads();

    const int b   = blockIdx.x;
    const int beg = bstarts[b];
    const int end = (b + 1 < nb) ? bstarts[b + 1] : n_edges;
    const int cnt = end - beg;

    // contiguous chunk per wave
    const int per = (cnt + 7) >> 3;
    const int we0 = beg + wv * per;
    const int we1 = min(we0 + per, end);

    int e = we0;
    for (; e + 8 <= we1; e += 8) {
        int2 p0 = pairs[e + 0]; int2 p1 = pairs[e + 1];
        int2 p2 = pairs[e + 2]; int2 p3 = pairs[e + 3];
        int2 p4 = pairs[e + 4]; int2 p5 = pairs[e + 5];
        int2 p6 = pairs[e + 6]; int2 p7 = pairs[e + 7];
        float x0 = x[(size_t)(p0.x & 0xFFFFFF) * D + lane];
        float x1 = x[(size_t)(p1.x & 0xFFFFFF) * D + lane];
        float x2 = x[(size_t)(p2.x & 0xFFFFFF) * D + lane];
        float x3 = x[(size_t)(p3.x & 0xFFFFFF) * D + lane];
        float x4 = x[(size_t)(p4.x & 0xFFFFFF) * D + lane];
        float x5 = x[(size_t)(p5.x & 0xFFFFFF) * D + lane];
        float x6 = x[(size_t)(p6.x & 0xFFFFFF) * D + lane];
        float x7 = x[(size_t)(p7.x & 0xFFFFFF) * D + lane];
        atomicAdd(&acc[((p0.x >> 24) << 6) + lane], __int_as_float(p0.y) * x0);
        atomicAdd(&acc[((p1.x >> 24) << 6) + lane], __int_as_float(p1.y) * x1);
        atomicAdd(&acc[((p2.x >> 24) << 6) + lane], __int_as_float(p2.y) * x2);
        atomicAdd(&acc[((p3.x >> 24) << 6) + lane], __int_as_float(p3.y) * x3);
        atomicAdd(&acc[((p4.x >> 24) << 6) + lane], __int_as_float(p4.y) * x4);
        atomicAdd(&acc[((p5.x >> 24) << 6) + lane], __int_as_float(p5.y) * x5);
        atomicAdd(&acc[((p6.x >> 24) << 6) + lane], __int_as_float(p6.y) * x6);
        atomicAdd(&acc[((p7.x >> 24) << 6) + lane], __int_as_float(p7.y) * x7);
    }
    for (; e < we1; ++e) {
        int2 p = pairs[e];
        float xv = x[(size_t)(p.x & 0xFFFFFF) * D + lane];
        atomicAdd(&acc[((p.x >> 24) << 6) + lane], __int_as_float(p.y) * xv);
    }
    __syncthreads();

    // epilogue: out[node0+tl][o] = sum_d acc[tl][d] * W[o][d], o = lane
    const int node0 = b * BKT;
    const int nn = min(BKT, n_nodes - node0);
    for (int tl = wv; tl < nn; tl += 8) {
        const float2* a2 = reinterpret_cast<const float2*>(&acc[tl << 6]);   // broadcast
        const float2* w2 = reinterpret_cast<const float2*>(&Wl[lane * 66]);  // 2-way = free
        float o = 0.f;
#pragma unroll
        for (int d2 = 0; d2 < 32; ++d2) {
            float2 aq = a2[d2];
            float2 wq = w2[d2];
            o += aq.x * wq.x + aq.y * wq.y;
        }
        out[(size_t)(node0 + tl) * D + lane] = o;
    }
}

extern "C" void kernel_launch(void* const* d_in, const int* in_sizes, int n_in,
                              void* d_out, int out_size, void* d_ws, size_t ws_size,
                              hipStream_t stream)
{
    const float* x   = (const float*)d_in[0];
    const float* W   = (const float*)d_in[1];
    const float* ew  = (const float*)d_in[2];
    const int*   src = (const int*)d_in[3];
    const int*   tgt = (const int*)d_in[4];

    const int n_nodes = in_sizes[0] / D;
    const int n_edges = in_sizes[2];
    const int nb = (n_nodes + BKT - 1) / BKT;

    // ---- workspace layout ----
    int* bcnt    = (int*)d_ws;                    // NBMAX
    int* bstarts = bcnt + NBMAX;                  // NBMAX
    int* bcur    = bstarts + NBMAX;               // NBMAX
    int2* pairs  = (int2*)(bcur + NBMAX);         // n_edges (8B-aligned: 3*NBMAX*4 % 8 == 0)

    const size_t need = (size_t)3 * NBMAX * sizeof(int) +
                        (size_t)n_edges * sizeof(int2);

    if (nb > NBMAX || n_nodes > (1 << 24) || ws_size < need) {
        // fallback: R1 atomic path (needs n_nodes*D floats)
        float* s = (float*)d_ws;
        hipMemsetAsync(s, 0, (size_t)n_nodes * D * sizeof(float), stream);
        gcn_scatter_kernel<<<(n_edges + 3) / 4, 256, 0, stream>>>(x, ew, src, tgt, s, n_edges);
        gcn_gemm_kernel<<<(n_nodes + 63) / 64, 256, 0, stream>>>(s, W, (float*)d_out, n_nodes);
        return;
    }

    hipMemsetAsync(bcnt, 0, (size_t)nb * sizeof(int), stream);

    const int ablocks = 128;
    const int epbA = (n_edges + ablocks - 1) / ablocks;
    bucket_hist_kernel<<<ablocks, 256, 0, stream>>>(tgt, bcnt, n_edges, nb, epbA);

    bucket_scan_kernel<<<1, 1024, 0, stream>>>(bcnt, bstarts, bcur, nb);

    const int cblocks = 256;
    const int epbC = (n_edges + cblocks - 1) / cblocks;
    bucket_scatter_kernel<<<cblocks, 256, 0, stream>>>(src, tgt, ew, bcur,
                                                       pairs, n_edges, nb, epbC);

    bucket_reduce_gemm_kernel<<<nb, 512, 0, stream>>>(
        x, W, bstarts, pairs, (float*)d_out, n_nodes, n_edges, nb);
}

// Round 7
// 129.517 us; speedup vs baseline: 3.8969x; 3.8969x over previous
//
#include <hip/hip_runtime.h>

// GCN block: delta = segment_sum( (x @ W^T)[source] * ew, target )
//          = segment_sum( x[source] * ew, target ) @ W^T   (linearity)
//
// R7: bucket counting-sort (BKT=128 nodes/bucket, proven R6 A/B/C) +
// per-bucket kernel that counting-sorts the bucket's edges in LDS, then
// does R5's register-accumulating segreduce (broadcast pair reads,
// readfirstlane scalar gather bases, 4-deep pipelined gathers) + fused
// 64x64 GEMM epilogue. VGPR<=64, LDS 36KB -> 4 blocks/CU, 32 waves/CU.
// (R6's LDS-atomic accumulator killed occupancy: 120 VGPR + 50KB LDS.)

#define D     64     // D_IN == D_OUT == 64
#define BKT   128    // nodes per bucket (t >> 7)
#define NBMAX 1024   // max buckets (scan kernel limit)
#define CAP   2048   // edges per in-LDS sort chunk

// ---------------- fallback: atomic edge scatter (R1) ----------------
__global__ __launch_bounds__(256) void gcn_scatter_kernel(
    const float* __restrict__ x, const float* __restrict__ ew,
    const int* __restrict__ src, const int* __restrict__ tgt,
    float* __restrict__ s, int n_edges)
{
    int lane = threadIdx.x & 63;
    int e = blockIdx.x * 4 + (threadIdx.x >> 6);
    if (e >= n_edges) return;
    int sn = src[e];
    int tn = tgt[e];
    float w = ew[e];
    float v = x[(size_t)sn * D + lane] * w;
    atomicAdd(&s[(size_t)tn * D + lane], v);
}

// ---------------- fallback: out = s @ W^T (R1) ----------------
__global__ __launch_bounds__(256) void gcn_gemm_kernel(
    const float* __restrict__ s, const float* __restrict__ W,
    float* __restrict__ out, int n_nodes)
{
    __shared__ float4 xs[64 * 17];
    const int tid  = threadIdx.x;
    const int lane = tid & 63;
    const int wid  = __builtin_amdgcn_readfirstlane(tid >> 6);
    const int row0 = blockIdx.x * 64;

    const float4* s4 = reinterpret_cast<const float4*>(s);
#pragma unroll
    for (int k = 0; k < 4; ++k) {
        int f  = tid + k * 256;
        int r  = f >> 4;
        int c4 = f & 15;
        float4 v = make_float4(0.f, 0.f, 0.f, 0.f);
        if (row0 + r < n_nodes)
            v = s4[(size_t)(row0 + r) * 16 + c4];
        xs[r * 17 + c4] = v;
    }
    __syncthreads();

    float acc[16];
#pragma unroll
    for (int j = 0; j < 16; ++j) acc[j] = 0.f;

    const int o0 = wid * 16;
    const float4* W4 = reinterpret_cast<const float4*>(W);
#pragma unroll
    for (int d4 = 0; d4 < 16; ++d4) {
        float4 xv = xs[lane * 17 + d4];
#pragma unroll
        for (int j = 0; j < 16; ++j) {
            float4 wv = W4[(size_t)(o0 + j) * 16 + d4];
            acc[j] += xv.x * wv.x + xv.y * wv.y + xv.z * wv.z + xv.w * wv.w;
        }
    }

    const int row = row0 + lane;
    if (row < n_nodes) {
        float4* out4 = reinterpret_cast<float4*>(out);
#pragma unroll
        for (int j4 = 0; j4 < 4; ++j4) {
            float4 v = make_float4(acc[j4 * 4 + 0], acc[j4 * 4 + 1],
                                   acc[j4 * 4 + 2], acc[j4 * 4 + 3]);
            out4[(size_t)row * 16 + wid * 4 + j4] = v;
        }
    }
}

// ---------------- A: bucket histogram (LDS-binned) ----------------
__global__ __launch_bounds__(256) void bucket_hist_kernel(
    const int* __restrict__ tgt, int* __restrict__ bcnt,
    int n_edges, int nb, int epb)
{
    __shared__ int h[NBMAX];
    const int tid = threadIdx.x;
    for (int i = tid; i < nb; i += 256) h[i] = 0;
    __syncthreads();
    const int e0 = blockIdx.x * epb;
    const int e1 = min(e0 + epb, n_edges);
    for (int e = e0 + tid; e < e1; e += 256)
        atomicAdd(&h[tgt[e] >> 7], 1);
    __syncthreads();
    for (int b = tid; b < nb; b += 256) {
        int c = h[b];
        if (c) atomicAdd(&bcnt[b], c);
    }
}

// ---------------- B: exclusive scan of bucket counts (nb <= 1024) ----------
__global__ __launch_bounds__(1024) void bucket_scan_kernel(
    const int* __restrict__ bcnt, int* __restrict__ bstarts,
    int* __restrict__ bcur, int nb)
{
    __shared__ int lds[1024];
    const int tid = threadIdx.x;
    int v = (tid < nb) ? bcnt[tid] : 0;
    lds[tid] = v;
    __syncthreads();
    for (int off = 1; off < 1024; off <<= 1) {
        int a = (tid >= off) ? lds[tid - off] : 0;
        __syncthreads();
        lds[tid] += a;
        __syncthreads();
    }
    if (tid < nb) {
        int st = lds[tid] - v;       // exclusive
        bstarts[tid] = st;
        bcur[tid]    = st;
    }
}

// ---------------- C: scatter edges into bucket-contiguous runs ----------
__global__ __launch_bounds__(256) void bucket_scatter_kernel(
    const int* __restrict__ src, const int* __restrict__ tgt,
    const float* __restrict__ ew, int* __restrict__ bcur,
    int2* __restrict__ pairs, int n_edges, int nb, int epb)
{
    __shared__ int h[NBMAX];        // counts, then rank counters
    __shared__ int base[NBMAX];
    const int tid = threadIdx.x;
    for (int i = tid; i < nb; i += 256) h[i] = 0;
    __syncthreads();
    const int e0 = blockIdx.x * epb;
    const int e1 = min(e0 + epb, n_edges);

    for (int e = e0 + tid; e < e1; e += 256)
        atomicAdd(&h[tgt[e] >> 7], 1);
    __syncthreads();

    for (int b = tid; b < nb; b += 256) {
        int c = h[b];
        base[b] = c ? atomicAdd(&bcur[b], c) : 0;
        h[b] = 0;                   // reuse as rank counter
    }
    __syncthreads();

    for (int e = e0 + tid; e < e1; e += 256) {
        int t = tgt[e];
        int b = t >> 7;
        int r = atomicAdd(&h[b], 1);
        pairs[base[b] + r] =
            make_int2(((t & (BKT - 1)) << 24) | src[e], __float_as_int(ew[e]));
    }
}

// ---------------- D: per-bucket LDS sort + register segreduce + GEMM ------
__global__ __launch_bounds__(512, 8) void bucket_sort_reduce_gemm_kernel(
    const float* __restrict__ x, const float* __restrict__ W,
    const int* __restrict__ bstarts, const int2* __restrict__ pairs,
    float* __restrict__ out, int n_nodes, int n_edges, int nb)
{
    __shared__ float Wl[64 * 66];       // 16.9 KB; W[o][d] at Wl[o*66+d]
    __shared__ int2  ep[CAP];           // 16 KB, node-sorted chunk
    __shared__ int   segIncl[BKT];      // inclusive per-node counts -> bounds
    __shared__ int   rankc[BKT];        // scatter cursors
    __shared__ float accRow[8][64];     // per-wave row buffer

    const int tid  = threadIdx.x;
    const int lane = tid & 63;
    const int wv   = tid >> 6;          // 0..7

    for (int i = tid; i < 64 * 64; i += 512)
        Wl[(i >> 6) * 66 + (i & 63)] = W[i];

    const int b   = blockIdx.x;
    const int beg = bstarts[b];
    const int end = (b + 1 < nb) ? bstarts[b + 1] : n_edges;

    float acc[16];
#pragma unroll
    for (int s = 0; s < 16; ++s) acc[s] = 0.f;

    for (int cbeg = beg; cbeg < end; cbeg += CAP) {
        const int ccnt = min(CAP, end - cbeg);

        // -- zero hist --
        if (tid < BKT) segIncl[tid] = 0;
        __syncthreads();

        // -- pass 1: histogram tloc --
        for (int i = tid; i < ccnt; i += 512) {
            unsigned px = (unsigned)pairs[cbeg + i].x;
            atomicAdd(&segIncl[px >> 24], 1);
        }
        __syncthreads();

        // -- 128-bin inclusive scan (Hillis-Steele, all threads barrier) --
        int myc = (tid < BKT) ? segIncl[tid] : 0;
        __syncthreads();
        for (int off = 1; off < BKT; off <<= 1) {
            int a = (tid < BKT && tid >= off) ? segIncl[tid - off] : 0;
            __syncthreads();
            if (tid < BKT) segIncl[tid] += a;
            __syncthreads();
        }
        if (tid < BKT) rankc[tid] = segIncl[tid] - myc;   // exclusive start
        __syncthreads();

        // -- pass 2: scatter into node-sorted LDS --
        for (int i = tid; i < ccnt; i += 512) {
            int2 p = pairs[cbeg + i];
            int tl = ((unsigned)p.x) >> 24;
            int pos = atomicAdd(&rankc[tl], 1);
            ep[pos] = p;
        }
        __syncthreads();

        // -- register segreduce: wave wv owns tloc = s*8+wv, s=0..15 --
#pragma unroll
        for (int s = 0; s < 16; ++s) {
            const int tl = s * 8 + wv;
            const int s0 = __builtin_amdgcn_readfirstlane(tl ? segIncl[tl - 1] : 0);
            const int s1 = __builtin_amdgcn_readfirstlane(segIncl[tl]);
            float a = acc[s];
            int e = s0;
            for (; e + 4 <= s1; e += 4) {
                int2 q0 = ep[e + 0]; int2 q1 = ep[e + 1];
                int2 q2 = ep[e + 2]; int2 q3 = ep[e + 3];
                // broadcast -> scalar base, lane offset gather
                int   i0 = __builtin_amdgcn_readfirstlane(q0.x) & 0xFFFFFF;
                int   i1 = __builtin_amdgcn_readfirstlane(q1.x) & 0xFFFFFF;
                int   i2 = __builtin_amdgcn_readfirstlane(q2.x) & 0xFFFFFF;
                int   i3 = __builtin_amdgcn_readfirstlane(q3.x) & 0xFFFFFF;
                float w0 = __int_as_float(__builtin_amdgcn_readfirstlane(q0.y));
                float w1 = __int_as_float(__builtin_amdgcn_readfirstlane(q1.y));
                float w2 = __int_as_float(__builtin_amdgcn_readfirstlane(q2.y));
                float w3 = __int_as_float(__builtin_amdgcn_readfirstlane(q3.y));
                float x0 = x[(size_t)i0 * D + lane];   // 4 independent gathers
                float x1 = x[(size_t)i1 * D + lane];
                float x2 = x[(size_t)i2 * D + lane];
                float x3 = x[(size_t)i3 * D + lane];
                a += w0 * x0; a += w1 * x1; a += w2 * x2; a += w3 * x3;
            }
            for (; e < s1; ++e) {
                int2 q = ep[e];
                int   i0 = __builtin_amdgcn_readfirstlane(q.x) & 0xFFFFFF;
                float w0 = __int_as_float(__builtin_amdgcn_readfirstlane(q.y));
                a += w0 * x[(size_t)i0 * D + lane];
            }
            acc[s] = a;
        }
        __syncthreads();   // protect ep/segIncl before next chunk
    }

    // -- epilogue: out[node][o] = sum_d acc * W[o][d], o = lane --
    const int node0 = b * BKT;
#pragma unroll
    for (int s = 0; s < 16; ++s) {
        const int tl = s * 8 + wv;
        const int node = node0 + tl;
        if (node < n_nodes) {
            accRow[wv][lane] = acc[s];
            asm volatile("s_waitcnt lgkmcnt(0)" ::: "memory");
            float o = 0.f;
            const float2* a2 = reinterpret_cast<const float2*>(&accRow[wv][0]);
            const float2* w2 = reinterpret_cast<const float2*>(&Wl[lane * 66]);
#pragma unroll
            for (int d2 = 0; d2 < 32; ++d2) {
                float2 aq = a2[d2];    // broadcast
                float2 wq = w2[d2];
                o += aq.x * wq.x + aq.y * wq.y;
            }
            out[(size_t)node * D + lane] = o;
            asm volatile("s_waitcnt lgkmcnt(0)" ::: "memory"); // drain before overwrite
        }
    }
}

extern "C" void kernel_launch(void* const* d_in, const int* in_sizes, int n_in,
                              void* d_out, int out_size, void* d_ws, size_t ws_size,
                              hipStream_t stream)
{
    const float* x   = (const float*)d_in[0];
    const float* W   = (const float*)d_in[1];
    const float* ew  = (const float*)d_in[2];
    const int*   src = (const int*)d_in[3];
    const int*   tgt = (const int*)d_in[4];

    const int n_nodes = in_sizes[0] / D;
    const int n_edges = in_sizes[2];
    const int nb = (n_nodes + BKT - 1) / BKT;

    // ---- workspace layout ----
    int*  bcnt    = (int*)d_ws;                   // NBMAX
    int*  bstarts = bcnt + NBMAX;                 // NBMAX
    int*  bcur    = bstarts + NBMAX;              // NBMAX
    int2* pairs   = (int2*)(bcur + NBMAX);        // n_edges (8B aligned)

    const size_t need = (size_t)3 * NBMAX * sizeof(int) +
                        (size_t)n_edges * sizeof(int2);

    if (nb > NBMAX || n_nodes > (1 << 24) || ws_size < need) {
        // fallback: R1 atomic path
        float* s = (float*)d_ws;
        hipMemsetAsync(s, 0, (size_t)n_nodes * D * sizeof(float), stream);
        gcn_scatter_kernel<<<(n_edges + 3) / 4, 256, 0, stream>>>(x, ew, src, tgt, s, n_edges);
        gcn_gemm_kernel<<<(n_nodes + 63) / 64, 256, 0, stream>>>(s, W, (float*)d_out, n_nodes);
        return;
    }

    hipMemsetAsync(bcnt, 0, (size_t)nb * sizeof(int), stream);

    const int ablocks = 128;
    const int epbA = (n_edges + ablocks - 1) / ablocks;
    bucket_hist_kernel<<<ablocks, 256, 0, stream>>>(tgt, bcnt, n_edges, nb, epbA);

    bucket_scan_kernel<<<1, 1024, 0, stream>>>(bcnt, bstarts, bcur, nb);

    const int cblocks = 256;
    const int epbC = (n_edges + cblocks - 1) / cblocks;
    bucket_scatter_kernel<<<cblocks, 256, 0, stream>>>(src, tgt, ew, bcur,
                                                       pairs, n_edges, nb, epbC);

    bucket_sort_reduce_gemm_kernel<<<nb, 512, 0, stream>>>(
        x, W, bstarts, pairs, (float*)d_out, n_nodes, n_edges, nb);
}